// Round 11
// baseline (429.569 us; speedup 1.0000x reference)
//
#include <hip/hip_runtime.h>

#define N_NODES 50000
#define N_EDGES 800000
#define D 128
#define NUM_GRAPHS 128
#define NBUCKET 196            // node buckets of 256
#define NSUB (NBUCKET * 8)     // 8 XCD-local sub-buckets per bucket
#define SUBCAP 1024            // expected 512 +- 23; 1024 = +22 sd

typedef __attribute__((ext_vector_type(8)))  short bfrag8;
typedef __attribute__((ext_vector_type(16))) float f32x16;

__device__ __forceinline__ float4 f4zero() { return make_float4(0.f, 0.f, 0.f, 0.f); }

__device__ __forceinline__ unsigned short f2bf(float f) {
    unsigned u = __float_as_uint(f);
    unsigned r = (u + 0x7fffu + ((u >> 16) & 1u)) >> 16;
    return (unsigned short)r;
}
__device__ __forceinline__ float bf2f(unsigned short b) {
    return __uint_as_float(((unsigned)b) << 16);
}
__device__ __forceinline__ float4 bf2f4(ushort4 u) {
    return make_float4(bf2f(u.x), bf2f(u.y), bf2f(u.z), bf2f(u.w));
}
__device__ __forceinline__ float4 bnrelu(float4 v, float4 a, float4 b) {
    v.x = fmaxf(a.x * v.x + b.x, 0.f);
    v.y = fmaxf(a.y * v.y + b.y, 0.f);
    v.z = fmaxf(a.z * v.z + b.z, 0.f);
    v.w = fmaxf(a.w * v.w + b.w, 0.f);
    return v;
}
__device__ __forceinline__ void acc4(float4& a, float4 u) {
    a.x += u.x; a.y += u.y; a.z += u.z; a.w += u.w;
}

// ===========================================================================
// prep: W->Wt (bf16 transposed), x->bf16, zero deg, zero stats, zero bcnt
// grid = 512 + 6250 + 196 + 3 + 98 = 7059
// ===========================================================================
__global__ __launch_bounds__(256) void prep_kernel(
    const float* __restrict__ W1, const float* __restrict__ W2,
    const float* __restrict__ x, short* __restrict__ Wt,
    ushort4* __restrict__ Hb, int* __restrict__ deg, float* __restrict__ stats,
    int* __restrict__ bcnt)
{
    int b = blockIdx.x, t = threadIdx.x;
    if (b < 512) {
        int idx = b * 256 + t;                 // 131072 = 8*128*128
        int m = idx >> 14, rem = idx & 16383;
        int k = rem >> 7, n = rem & 127;
        const float* W = (m < 4) ? (W1 + (size_t)m * 16384)
                                 : (W2 + (size_t)(m - 4) * 16384);
        Wt[(size_t)m * 16384 + n * 128 + k] = (short)f2bf(W[k * 128 + n]);
    } else if (b < 6762) {
        int i = (b - 512) * 256 + t;           // N*32 = 1,600,000 exactly
        float4 v = ((const float4*)x)[i];
        Hb[i] = make_ushort4(f2bf(v.x), f2bf(v.y), f2bf(v.z), f2bf(v.w));
    } else if (b < 6958) {
        int i = (b - 6762) * 256 + t;
        if (i < N_NODES) deg[i] = 0;
    } else if (b < 6961) {
        int i = (b - 6958) * 256 + t;          // 768 floats: 3 x (sum||sq)
        stats[i] = 0.f;
    } else {
        int i = (b - 6961) * 256 + t;          // NSUB*16 = 25088 ints
        if (i < NSUB * 16) bcnt[i] = 0;
    }
}

// ===========================================================================
// CSR build, bucketed 3-phase (replaces hist+fill; kills the 55MB
// cross-XCD write amplification of scattered 4B CSR writes).
// P1: edge -> sub-bucket (XCD-local via blockIdx&7); pack src|dstlocal.
// ===========================================================================
__global__ __launch_bounds__(256) void bucket_kernel(
    const int* __restrict__ src, const int* __restrict__ dst,
    int* __restrict__ bcnt, unsigned* __restrict__ bpack)
{
    int e = blockIdx.x * 256 + threadIdx.x;
    if (e >= N_EDGES) return;
    int d = dst[e];
    int s = src[e];
    int c = (d >> 8) * 8 + (blockIdx.x & 7);
    int pos = atomicAdd(&bcnt[c * 16], 1);     // 1 counter per cache line
    if (pos < SUBCAP)
        bpack[(size_t)c * SUBCAP + pos] = (unsigned)s | ((unsigned)(d & 255) << 16);
}

// P2: per-bucket LDS histogram -> deg (coalesced write, no global atomics)
__global__ __launch_bounds__(256) void deg_kernel(
    const int* __restrict__ bcnt, const unsigned* __restrict__ bpack,
    int* __restrict__ deg)
{
    __shared__ int cnt[256];
    int b = blockIdx.x, t = threadIdx.x;
    cnt[t] = 0;
    __syncthreads();
    for (int s = 0; s < 8; ++s) {
        int c = b * 8 + s;
        int n = min(bcnt[c * 16], SUBCAP);
        const unsigned* seg = bpack + (size_t)c * SUBCAP;
        for (int i = t; i < n; i += 256)
            atomicAdd(&cnt[(seg[i] >> 16) & 255], 1);
    }
    __syncthreads();
    int node = b * 256 + t;
    if (node < N_NODES) deg[node] = cnt[t];
}

__global__ __launch_bounds__(256) void scan_block_kernel(
    const int* __restrict__ deg, int* __restrict__ row_ptr,
    int* __restrict__ blockSum)
{
    __shared__ int wsum[4];
    int t = threadIdx.x, b = blockIdx.x;
    int i = b * 256 + t;
    int v = (i < N_NODES) ? deg[i] : 0;
    int lane = t & 63, wid = t >> 6;
    #pragma unroll
    for (int off = 1; off < 64; off <<= 1) {
        int u = __shfl_up(v, off, 64);
        if (lane >= off) v += u;
    }
    if (lane == 63) wsum[wid] = v;
    __syncthreads();
    int add = 0;
    for (int w = 0; w < wid; ++w) add += wsum[w];
    v += add;
    if (i < N_NODES) row_ptr[i + 1] = v;
    if (t == 255) blockSum[b] = v;
}

__global__ __launch_bounds__(256) void scan_fixup_kernel(
    const int* __restrict__ blockSum, int* __restrict__ row_ptr, int nb)
{
    __shared__ int wsum[4];
    __shared__ int sbuf[256];
    int t = threadIdx.x, b = blockIdx.x;
    int v = (t < nb) ? blockSum[t] : 0;
    int lane = t & 63, wid = t >> 6;
    #pragma unroll
    for (int off = 1; off < 64; off <<= 1) {
        int u = __shfl_up(v, off, 64);
        if (lane >= off) v += u;
    }
    if (lane == 63) wsum[wid] = v;
    __syncthreads();
    int add = 0;
    for (int w = 0; w < wid; ++w) add += wsum[w];
    sbuf[t] = v + add;
    __syncthreads();
    if (b == 0 && t == 0) row_ptr[0] = 0;
    if (b > 0) {
        int off = sbuf[b - 1];
        int i = b * 256 + t;
        if (i < N_NODES) row_ptr[i + 1] += off;
    }
}

// P3: per-bucket fill; bucket's CSR range (~16KB) written by one block
__global__ __launch_bounds__(256) void csrfill_kernel(
    const int* __restrict__ bcnt, const unsigned* __restrict__ bpack,
    const int* __restrict__ row_ptr, int* __restrict__ csr_src)
{
    __shared__ int cur[256];
    __shared__ int rp[256];
    int b = blockIdx.x, t = threadIdx.x;
    cur[t] = 0;
    int node = b * 256 + t;
    rp[t] = (node < N_NODES) ? row_ptr[node] : 0;
    __syncthreads();
    for (int s = 0; s < 8; ++s) {
        int c = b * 8 + s;
        int n = min(bcnt[c * 16], SUBCAP);
        const unsigned* seg = bpack + (size_t)c * SUBCAP;
        for (int i = t; i < n; i += 256) {
            unsigned p = seg[i];
            int dl = (p >> 16) & 255;
            int pos = atomicAdd(&cur[dl], 1);
            csr_src[rp[dl] + pos] = (int)(p & 0xffffu);
        }
    }
}

// ===========================================================================
// Fused gather (R6-proven body) + in-kernel BN-scale derivation:
//   A[n] = bf16( (1+eps)*y(h[n]) + sum_{j in N(n)} y(h[j]) )
// y(v) = relu(a*v + b) with a,b computed from prev layer's raw stats.
// 32 lanes per node, ushort4/lane, 8-deep unroll, fp32 accumulation.
// ===========================================================================
__global__ __launch_bounds__(256) void gather_kernel(
    const ushort4* __restrict__ H, const int* __restrict__ row_ptr,
    const int* __restrict__ csr_src,
    const float* __restrict__ stats,      // [256] sum||sq of prev layer, or null
    const float* __restrict__ gamma, const float* __restrict__ beta,
    const float* __restrict__ epsp,
    ushort4* __restrict__ A)
{
    int node = blockIdx.x * 8 + (threadIdx.x >> 5);
    if (node >= N_NODES) return;
    int lane = threadIdx.x & 31;
    const bool bn = (stats != nullptr);
    float4 sa = make_float4(1.f, 1.f, 1.f, 1.f);
    float4 sb = f4zero();
    if (bn) {
        const float invN = 1.0f / (float)N_NODES;
        float m0 = stats[lane * 4 + 0] * invN, m1 = stats[lane * 4 + 1] * invN;
        float m2 = stats[lane * 4 + 2] * invN, m3 = stats[lane * 4 + 3] * invN;
        sa.x = gamma[lane * 4 + 0] * rsqrtf(stats[128 + lane * 4 + 0] * invN - m0 * m0 + 1e-5f);
        sa.y = gamma[lane * 4 + 1] * rsqrtf(stats[128 + lane * 4 + 1] * invN - m1 * m1 + 1e-5f);
        sa.z = gamma[lane * 4 + 2] * rsqrtf(stats[128 + lane * 4 + 2] * invN - m2 * m2 + 1e-5f);
        sa.w = gamma[lane * 4 + 3] * rsqrtf(stats[128 + lane * 4 + 3] * invN - m3 * m3 + 1e-5f);
        sb.x = beta[lane * 4 + 0] - m0 * sa.x;
        sb.y = beta[lane * 4 + 1] - m1 * sa.y;
        sb.z = beta[lane * 4 + 2] - m2 * sa.z;
        sb.w = beta[lane * 4 + 3] - m3 * sa.w;
    }
    float eps1 = 1.0f + *epsp;
    int beg = row_ptr[node], end = row_ptr[node + 1];

    float4 v = bf2f4(H[node * 32 + lane]);
    if (bn) v = bnrelu(v, sa, sb);
    float4 acc = make_float4(eps1 * v.x, eps1 * v.y, eps1 * v.z, eps1 * v.w);

    for (int base = beg; base < end; base += 32) {
        int idx = (base + lane < end) ? csr_src[base + lane] : 0;
        int cnt = min(32, end - base);
        int j = 0;
        for (; j + 8 <= cnt; j += 8) {
            int s0 = __shfl(idx, j + 0, 32), s1 = __shfl(idx, j + 1, 32);
            int s2 = __shfl(idx, j + 2, 32), s3 = __shfl(idx, j + 3, 32);
            int s4 = __shfl(idx, j + 4, 32), s5 = __shfl(idx, j + 5, 32);
            int s6 = __shfl(idx, j + 6, 32), s7 = __shfl(idx, j + 7, 32);
            float4 u0 = bf2f4(H[s0 * 32 + lane]);
            float4 u1 = bf2f4(H[s1 * 32 + lane]);
            float4 u2 = bf2f4(H[s2 * 32 + lane]);
            float4 u3 = bf2f4(H[s3 * 32 + lane]);
            float4 u4 = bf2f4(H[s4 * 32 + lane]);
            float4 u5 = bf2f4(H[s5 * 32 + lane]);
            float4 u6 = bf2f4(H[s6 * 32 + lane]);
            float4 u7 = bf2f4(H[s7 * 32 + lane]);
            if (bn) {
                u0 = bnrelu(u0, sa, sb); u1 = bnrelu(u1, sa, sb);
                u2 = bnrelu(u2, sa, sb); u3 = bnrelu(u3, sa, sb);
                u4 = bnrelu(u4, sa, sb); u5 = bnrelu(u5, sa, sb);
                u6 = bnrelu(u6, sa, sb); u7 = bnrelu(u7, sa, sb);
            }
            acc4(acc, u0); acc4(acc, u1); acc4(acc, u2); acc4(acc, u3);
            acc4(acc, u4); acc4(acc, u5); acc4(acc, u6); acc4(acc, u7);
        }
        for (; j < cnt; ++j) {
            int s = __shfl(idx, j, 32);
            float4 u = bf2f4(H[s * 32 + lane]);
            if (bn) u = bnrelu(u, sa, sb);
            acc4(acc, u);
        }
    }
    A[node * 32 + lane] = make_ushort4(f2bf(acc.x), f2bf(acc.y),
                                       f2bf(acc.z), f2bf(acc.w));
}

// ===========================================================================
// Fused MLP (R10-proven):  z2 = (relu(A @ W1 + b1)) @ W2 + b2, bf16 MFMA
// 32x32x16. Block = 256 thr = 4 waves over a 64-row tile: rg=wv&1 rows,
// ch=wv>>1 col-half. XOR-chunk swizzled Wlds/zlds.
// ===========================================================================
__global__ __launch_bounds__(256, 3) void mlp_fused_kernel(
    const ushort* __restrict__ A,
    const short* __restrict__ Wt1,
    const short* __restrict__ Wt2,
    const float* __restrict__ bias1,
    const float* __restrict__ bias2,
    ushort* __restrict__ Hout,
    float* __restrict__ statsSum,
    float* __restrict__ statsSq,
    int M)
{
    __shared__ __align__(16) short Wlds[128 * 128];   // 32 KB
    __shared__ __align__(16) short zlds[2][32 * 128]; // 16 KB
    __shared__ float ssum[128];
    __shared__ float ssq[128];

    const int tid  = threadIdx.x;
    const int wv   = tid >> 6;
    const int lane = tid & 63;
    const int half = lane >> 5;
    const int ln   = lane & 31;
    const int rg   = wv & 1;
    const int ch   = wv >> 1;
    const int row0 = blockIdx.x * 64 + rg * 32;
    const bool doStats = (statsSum != nullptr);
    if (doStats && tid < 128) { ssum[tid] = 0.f; ssq[tid] = 0.f; }

    short* zw = &zlds[rg][0];

    // ---- stage W1 -> Wlds (chunk c of row n at c^(n&15)) ----
    {
        const int4* Wg = (const int4*)Wt1;
        int4* Wl = (int4*)Wlds;
        #pragma unroll
        for (int i = 0; i < 8; ++i) {
            int id = i * 256 + tid;            // 2048 int4
            int n = id >> 4, c = id & 15;
            Wl[n * 16 + (c ^ (n & 15))] = Wg[id];
        }
    }
    __syncthreads();   // S0: W1 staged, ssum init

    // ---- GEMM1: z1 = relu(A@W1 + b1) -> zlds[rg] ----
    {
        f32x16 acc[2];
        #pragma unroll
        for (int ci = 0; ci < 2; ++ci)
            #pragma unroll
            for (int r = 0; r < 16; ++r) acc[ci][r] = 0.f;

        bfrag8 af[8];
        int rowc = min(row0 + ln, M - 1);
        const ushort* ap = A + (size_t)rowc * 128 + half * 8;
        #pragma unroll
        for (int kk = 0; kk < 8; ++kk)
            af[kk] = *(const bfrag8*)(ap + kk * 16);

        #pragma unroll
        for (int kk = 0; kk < 8; ++kk) {
            #pragma unroll
            for (int ci = 0; ci < 2; ++ci) {
                int n = (ch * 2 + ci) * 32 + ln;
                int c = kk * 2 + half;
                bfrag8 bf = *(const bfrag8*)(Wlds + n * 128 + ((c ^ (n & 15)) << 3));
                acc[ci] = __builtin_amdgcn_mfma_f32_32x32x16_bf16(
                    af[kk], bf, acc[ci], 0, 0, 0);
            }
        }
        #pragma unroll
        for (int ci = 0; ci < 2; ++ci) {
            int col = (ch * 2 + ci) * 32 + ln;
            int cc = col >> 3, co = col & 7;
            float bv = bias1[col];
            #pragma unroll
            for (int r = 0; r < 16; ++r) {
                int rloc = (r & 3) + 8 * (r >> 2) + 4 * half;
                float v = fmaxf(acc[ci][r] + bv, 0.f);
                zw[rloc * 128 + ((cc ^ (rloc & 15)) << 3) + co] = (short)f2bf(v);
            }
        }
    }
    __syncthreads();   // S1: z1 complete, G1 Wlds reads done

    // ---- stage W2 -> Wlds; preload af2 from zlds[rg] ----
    bfrag8 af2[8];
    #pragma unroll
    for (int kk = 0; kk < 8; ++kk) {
        int c = kk * 2 + half;
        af2[kk] = *(const bfrag8*)(zw + ln * 128 + ((c ^ (ln & 15)) << 3));
    }
    {
        const int4* Wg = (const int4*)Wt2;
        int4* Wl = (int4*)Wlds;
        #pragma unroll
        for (int i = 0; i < 8; ++i) {
            int id = i * 256 + tid;
            int n = id >> 4, c = id & 15;
            Wl[n * 16 + (c ^ (n & 15))] = Wg[id];
        }
    }
    __syncthreads();   // S2: W2 staged, all af2 preloads done

    // ---- GEMM2: z2 = z1 @ W2 + b2 -> zlds[rg]; stats on fp32 values ----
    {
        f32x16 acc[2];
        #pragma unroll
        for (int ci = 0; ci < 2; ++ci)
            #pragma unroll
            for (int r = 0; r < 16; ++r) acc[ci][r] = 0.f;

        #pragma unroll
        for (int kk = 0; kk < 8; ++kk) {
            #pragma unroll
            for (int ci = 0; ci < 2; ++ci) {
                int n = (ch * 2 + ci) * 32 + ln;
                int c = kk * 2 + half;
                bfrag8 bf = *(const bfrag8*)(Wlds + n * 128 + ((c ^ (n & 15)) << 3));
                acc[ci] = __builtin_amdgcn_mfma_f32_32x32x16_bf16(
                    af2[kk], bf, acc[ci], 0, 0, 0);
            }
        }
        #pragma unroll
        for (int ci = 0; ci < 2; ++ci) {
            int col = (ch * 2 + ci) * 32 + ln;
            int cc = col >> 3, co = col & 7;
            float bv = bias2[col];
            float s = 0.f, sq = 0.f;
            #pragma unroll
            for (int r = 0; r < 16; ++r) {
                int rloc = (r & 3) + 8 * (r >> 2) + 4 * half;
                float v = acc[ci][r] + bv;
                zw[rloc * 128 + ((cc ^ (rloc & 15)) << 3) + co] = (short)f2bf(v);
                if (row0 + rloc < M) { s += v; sq += v * v; }
            }
            if (doStats) {
                s  += __shfl_xor(s, 32);
                sq += __shfl_xor(sq, 32);
                if (half == 0) {
                    atomicAdd(&ssum[col], s);
                    atomicAdd(&ssq[col], sq);
                }
            }
        }
    }
    __syncthreads();   // S3: z2 complete, ssum atomics done

    // ---- coalesced store: zlds -> Hout (64 rows x 16 int4) ----
    {
        int4* Ho = (int4*)Hout;
        #pragma unroll
        for (int i = 0; i < 4; ++i) {
            int id = i * 256 + tid;            // 1024 int4
            int r = id >> 4, c = id & 15;
            int rl = r & 31;
            int grow = blockIdx.x * 64 + r;
            if (grow < M)
                Ho[(size_t)grow * 16 + c] =
                    ((const int4*)&zlds[r >> 5][0])[rl * 16 + (c ^ (rl & 15))];
        }
    }
    if (doStats && tid < 128) {
        atomicAdd(&statsSum[tid], ssum[tid]);
        atomicAdd(&statsSq[tid],  ssq[tid]);
    }
}

// ===========================================================================
// global_add_pool (R6-proven): batch sorted -> run-length accumulate.
// ===========================================================================
__global__ __launch_bounds__(256) void pool_kernel(
    const ushort4* __restrict__ H, const int* __restrict__ batch,
    float* __restrict__ out)
{
    int c4 = threadIdx.x & 31;
    int nl = threadIdx.x >> 5;
    int node0 = blockIdx.x * 256;
    float4 acc = f4zero();
    int gcur = -1;
    for (int i = nl; i < 256; i += 8) {
        int n = node0 + i;
        if (n >= N_NODES) break;
        int g = batch[n];
        if (g != gcur) {
            if (gcur >= 0) {
                float* o = out + gcur * D + c4 * 4;
                atomicAdd(o + 0, acc.x); atomicAdd(o + 1, acc.y);
                atomicAdd(o + 2, acc.z); atomicAdd(o + 3, acc.w);
            }
            gcur = g;
            acc = f4zero();
        }
        float4 v = bf2f4(H[n * 32 + c4]);
        acc4(acc, v);
    }
    if (gcur >= 0) {
        float* o = out + gcur * D + c4 * 4;
        atomicAdd(o + 0, acc.x); atomicAdd(o + 1, acc.y);
        atomicAdd(o + 2, acc.z); atomicAdd(o + 3, acc.w);
    }
}

extern "C" void kernel_launch(void* const* d_in, const int* in_sizes, int n_in,
                              void* d_out, int out_size, void* d_ws, size_t ws_size,
                              hipStream_t stream)
{
    const float* x     = (const float*)d_in[0];
    const int*   ei    = (const int*)d_in[1];
    const int*   batch = (const int*)d_in[2];
    const float* W1    = (const float*)d_in[3];
    const float* b1    = (const float*)d_in[4];
    const float* W2    = (const float*)d_in[5];
    const float* b2    = (const float*)d_in[6];
    const float* eps   = (const float*)d_in[7];
    const float* gamma = (const float*)d_in[8];
    const float* beta  = (const float*)d_in[9];
    float* out = (float*)d_out;

    // ---- workspace layout ----
    unsigned short* Hb  = (unsigned short*)d_ws;          // [N,128] bf16
    unsigned short* Abf = Hb + (size_t)N_NODES * D;       // [N,128] bf16
    float* stats    = (float*)(Abf + (size_t)N_NODES * D);// [3][256] sum||sq
    int*   deg      = (int*)(stats + 3 * 256);            // [N]
    int*   row_ptr  = deg + N_NODES;                      // [N+1]
    int*   blockSum = row_ptr + N_NODES + 1;              // [256]
    int*   bcnt     = blockSum + 256;                     // [NSUB*16] padded
    unsigned* bpack = (unsigned*)(bcnt + NSUB * 16);      // [NSUB*SUBCAP]
    int*   csr_src  = (int*)(bpack + (size_t)NSUB * SUBCAP); // [E]
    short* Wt       = (short*)(csr_src + N_EDGES);        // [8][128][128]

    const int* src = ei;
    const int* dst = ei + N_EDGES;

    const int edgeBlocks   = (N_EDGES + 255) / 256;      // 3125
    const int scanBlocks   = (N_NODES + 255) / 256;      // 196
    const int gatherBlocks = (N_NODES + 7) / 8;          // 6250
    const int gemmBlocks   = (N_NODES + 63) / 64;        // 782

    prep_kernel<<<7059, 256, 0, stream>>>(W1, W2, x, Wt, (ushort4*)Hb,
                                          deg, stats, bcnt);
    bucket_kernel<<<edgeBlocks, 256, 0, stream>>>(src, dst, bcnt, bpack);
    deg_kernel<<<NBUCKET, 256, 0, stream>>>(bcnt, bpack, deg);
    scan_block_kernel<<<scanBlocks, 256, 0, stream>>>(deg, row_ptr, blockSum);
    scan_fixup_kernel<<<scanBlocks, 256, 0, stream>>>(blockSum, row_ptr, scanBlocks);
    csrfill_kernel<<<NBUCKET, 256, 0, stream>>>(bcnt, bpack, row_ptr, csr_src);

    for (int layer = 0; layer < 4; ++layer) {
        const bool bn = (layer < 3);
        const float* statPrev = (layer == 0) ? nullptr : stats + (layer - 1) * 256;
        int gl = (layer > 0) ? layer - 1 : 0;
        gather_kernel<<<gatherBlocks, 256, 0, stream>>>(
            (const ushort4*)Hb, row_ptr, csr_src, statPrev,
            gamma + (size_t)gl * D, beta + (size_t)gl * D,
            eps + layer, (ushort4*)Abf);
        mlp_fused_kernel<<<gemmBlocks, 256, 0, stream>>>(
            Abf, Wt + (size_t)layer * 16384, Wt + (size_t)(4 + layer) * 16384,
            b1 + (size_t)layer * D, b2 + (size_t)layer * D, Hb,
            bn ? stats + layer * 256 : nullptr,
            bn ? stats + layer * 256 + 128 : nullptr, N_NODES);
    }

    hipMemsetAsync(out, 0, (size_t)NUM_GRAPHS * D * sizeof(float), stream);
    pool_kernel<<<scanBlocks, 256, 0, stream>>>(
        (const ushort4*)Hb, batch, out);
}